// Round 13
// baseline (91.064 us; speedup 1.0000x reference)
//
#include <hip/hip_runtime.h>
#include <hip/hip_bf16.h>
#include <stdint.h>

typedef __attribute__((ext_vector_type(8))) __bf16 bf16x8;
typedef __attribute__((ext_vector_type(4))) float f32x4;
typedef __attribute__((ext_vector_type(16))) float f32x16;

static constexpr int Bb = 32, Ss = 512, Dd = 1024, Rr = 256;

__device__ __forceinline__ void gload_lds16(const void* g, void* l) {
  __builtin_amdgcn_global_load_lds(
      (const __attribute__((address_space(1))) void*)g,
      (__attribute__((address_space(3))) void*)l, 16, 0, 0);
}

// ---- prep: Bt[512][1024] bf16. rows 0-255 = L^T, rows 256-511 = R ----------
__global__ __launch_bounds__(256) void prep_kernel(
    const float* __restrict__ L, const float* __restrict__ R,
    __bf16* __restrict__ Bt) {
  int i = blockIdx.x * 256 + threadIdx.x;  // 0 .. 512*1024-1 exactly
  int n = i >> 10;
  int d = i & (Dd - 1);
  float v = (n < Rr) ? L[d * Rr + n] : R[(size_t)(n - Rr) * Dd + d];
  Bt[i] = (__bf16)v;
}

// ---- stage 1: C[16384,512] = batch_f32[16384,1024] x Bt[512,1024]^T --------
// 32x32x16 MFMA variant: HALF the LDS bytes/FLOP, 1/4 the MFMA instructions.
// A is loaded DIRECTLY from global fp32 into the wave's fragment registers
// (layout row=lane&31, k-half=lane>>5) -> no A-LDS, no A-sync; pipelined one
// K-tile ahead in named regs, cvt to bf16 in-reg. Only B (8KB/tile) is LDS,
// double-buffered, staged via gload_lds w/ involution swizzle g^(row&3),
// fenced by ONE full-drain __syncthreads per tile (R10-proven pattern).
// 128x128 tile, BK=32, 4 waves (64x64 each, acc 2x2xf32x16), 512 blocks.
__global__ __launch_bounds__(256, 3) void proj_gemm(
    const float* __restrict__ batch,
    const __bf16* __restrict__ Bt,   // [512][1024]
    __bf16* __restrict__ outL,       // [16384][256]
    __bf16* __restrict__ outR) {     // [16384][256]
  // XCD-chunked (bijective, 512 = 8*64): 4 nt-siblings of an mt co-XCD.
  const int s = ((blockIdx.x & 7) << 6) + (blockIdx.x >> 3);
  const int mt = s >> 2;  // 0..127
  const int nt = s & 3;   // 0..3
  const int m0 = mt * 128, n0 = nt * 128;

  __shared__ __align__(16) char smem[16384];  // B [128][32]bf16 x 2 bufs

  const int t = threadIdx.x;
  const int lane = t & 63;
  const int wave = t >> 6;
  const int wr = wave >> 1, wc = wave & 1;  // 2x2 waves, 64x64 each

  f32x16 acc[2][2] = {};

  // A fragment addressing: row = m0 + wr*64 + mi*32 + (lane&31),
  //                        k   = k0 + ks*16 + (lane>>5)*8
  const float* abase =
      batch + (size_t)(m0 + wr * 64 + (lane & 31)) * Dd + (lane >> 5) * 8;

  f32x4 anext[8];   // tile t+1 raw fp32 (fully unrolled indexing only)
  bf16x8 acur[4];   // tile t fragments [mi*2+ks]

  auto loadAraw = [&](int k0) {
#pragma unroll
    for (int mi = 0; mi < 2; ++mi)
#pragma unroll
      for (int ks = 0; ks < 2; ++ks) {
        const float* p = abase + (size_t)mi * 32 * Dd + k0 + ks * 16;
        anext[(mi * 2 + ks) * 2] = *(const f32x4*)p;
        anext[(mi * 2 + ks) * 2 + 1] = *(const f32x4*)(p + 4);
      }
  };
  auto cvtA = [&]() {
#pragma unroll
    for (int q = 0; q < 4; ++q) {
      f32x4 lo = anext[2 * q], hi = anext[2 * q + 1];
      bf16x8 v;
      v[0] = (__bf16)lo[0]; v[1] = (__bf16)lo[1];
      v[2] = (__bf16)lo[2]; v[3] = (__bf16)lo[3];
      v[4] = (__bf16)hi[0]; v[5] = (__bf16)hi[1];
      v[6] = (__bf16)hi[2]; v[7] = (__bf16)hi[3];
      acur[q] = v;
    }
  };
  auto stageB = [&](int buf, int k0) {
    char* Bbuf = smem + buf * 8192;
#pragma unroll
    for (int p = 0; p < 2; ++p) {
      int e = p * 256 + t;
      int row = e >> 2, g = e & 3;
      int gs = g ^ (row & 3);  // inverse-swizzled SOURCE, linear LDS dest
      gload_lds16(Bt + (size_t)(n0 + row) * Dd + k0 + gs * 8, Bbuf + e * 16);
    }
  };

  // prologue
  loadAraw(0);
  stageB(0, 0);
  cvtA();          // compiler inserts counted vmcnt for anext deps
  __syncthreads(); // full drain: B(0) DMA landed

#pragma unroll 1
  for (int tt = 0; tt < 32; ++tt) {
    const int buf = tt & 1;
    const char* Bbuf = smem + buf * 8192;
    if (tt < 31) stageB(buf ^ 1, tt * 32 + 32);  // DMA under compute

    // k-step 0 (K=16): 2 B-frag reads + 4 MFMA
    bf16x8 b0[2], b1[2];
#pragma unroll
    for (int ni = 0; ni < 2; ++ni) {
      int row = wc * 64 + ni * 32 + (lane & 31);
      int kg = 0 * 2 + (lane >> 5);
      b0[ni] = *(const bf16x8*)(Bbuf + (row * 4 + (kg ^ (row & 3))) * 16);
    }
#pragma unroll
    for (int mi = 0; mi < 2; ++mi)
#pragma unroll
      for (int ni = 0; ni < 2; ++ni)
        acc[mi][ni] = __builtin_amdgcn_mfma_f32_32x32x16_bf16(
            acur[mi * 2 + 0], b0[ni], acc[mi][ni], 0, 0, 0);

    if (tt < 31) loadAraw(tt * 32 + 32);  // A(t+1) in flight under k-step 1

    // k-step 1: 2 B-frag reads + 4 MFMA
#pragma unroll
    for (int ni = 0; ni < 2; ++ni) {
      int row = wc * 64 + ni * 32 + (lane & 31);
      int kg = 1 * 2 + (lane >> 5);
      b1[ni] = *(const bf16x8*)(Bbuf + (row * 4 + (kg ^ (row & 3))) * 16);
    }
#pragma unroll
    for (int mi = 0; mi < 2; ++mi)
#pragma unroll
      for (int ni = 0; ni < 2; ++ni)
        acc[mi][ni] = __builtin_amdgcn_mfma_f32_32x32x16_bf16(
            acur[mi * 2 + 1], b1[ni], acc[mi][ni], 0, 0, 0);

    __syncthreads();               // full drain: B(t+1) DMA + reads retired
    if (tt < 31) cvtA();           // counted vmcnt on anext; regs for t+1
  }

  // epilogue: 32x32 C/D layout: col=lane&31, row=(r&3)+8*(r>>2)+4*(lane>>5)
  __bf16* out = (n0 < Rr) ? outL : outR;
  const int cb = n0 & (Rr - 1);
  const int colb = lane & 31, rowb = 4 * (lane >> 5);
#pragma unroll
  for (int mi = 0; mi < 2; ++mi)
#pragma unroll
    for (int ni = 0; ni < 2; ++ni) {
      int rbase = m0 + wr * 64 + mi * 32 + rowb;
      int c = cb + wc * 64 + ni * 32 + colb;
#pragma unroll
      for (int r = 0; r < 16; ++r) {
        int row = rbase + (r & 3) + 8 * (r >> 2);
        out[(size_t)row * Rr + c] = (__bf16)acc[mi][ni][r];
      }
    }
}

// ---- stage 2: logits[b] = left[b] @ right[b]^T + bias ----------------------
// Per batch: C[512,512] f32 = A[512,256] x Bt[512,256], both bf16 K-contig.
// 64x128 tile, BK=64, single-buffer 24KB, swizzled. 1024 blocks (4/CU).
// UNCHANGED control.
__global__ __launch_bounds__(256, 4) void score_gemm(
    const __bf16* __restrict__ left,
    const __bf16* __restrict__ right,
    const float* __restrict__ biasp,
    float* __restrict__ out) {
  const int nt = blockIdx.x;  // 0..3
  const int mt = blockIdx.y;  // 0..7
  const int bz = blockIdx.z;  // 0..31
  const __bf16* A = left + (size_t)bz * Ss * Rr;
  const __bf16* B = right + (size_t)bz * Ss * Rr;
  float* O = out + (size_t)bz * Ss * Ss;
  const int m0 = mt * 64, n0 = nt * 128;

  __shared__ __align__(16) char smem[24576];
  const int t = threadIdx.x;
  const int lane = t & 63;
  const int wave = t >> 6;
  const int wr = wave >> 1, wc = wave & 1;

  f32x4 acc[2][4] = {};

  for (int it = 0; it < 4; ++it) {
    const int k0 = it * 64;
    __syncthreads();
#pragma unroll
    for (int q = 0; q < 2; ++q) {
      int e = q * 256 + t;
      int row = e >> 3, g = e & 7;
      int gsrc = g ^ (row & 7);
      gload_lds16(A + (size_t)(m0 + row) * Rr + k0 + gsrc * 8, smem + e * 16);
    }
#pragma unroll
    for (int q = 0; q < 4; ++q) {
      int e = q * 256 + t;
      int row = e >> 3, g = e & 7;
      int gsrc = g ^ (row & 7);
      gload_lds16(B + (size_t)(n0 + row) * Rr + k0 + gsrc * 8,
                  smem + 8192 + e * 16);
    }
    __syncthreads();

#pragma unroll
    for (int kk = 0; kk < 2; ++kk) {
      bf16x8 a[2], b[4];
#pragma unroll
      for (int m = 0; m < 2; ++m) {
        int row = wr * 32 + m * 16 + (lane & 15);
        int g = kk * 4 + (lane >> 4);
        a[m] = *(const bf16x8*)(smem + (row * 8 + (g ^ (row & 7))) * 16);
      }
#pragma unroll
      for (int n = 0; n < 4; ++n) {
        int row = wc * 64 + n * 16 + (lane & 15);
        int g = kk * 4 + (lane >> 4);
        b[n] = *(const bf16x8*)(smem + 8192 +
                                (row * 8 + (g ^ (row & 7))) * 16);
      }
#pragma unroll
      for (int m = 0; m < 2; ++m)
#pragma unroll
        for (int n = 0; n < 4; ++n)
          acc[m][n] = __builtin_amdgcn_mfma_f32_16x16x32_bf16(a[m], b[n],
                                                              acc[m][n], 0, 0, 0);
    }
  }

  const float bias = *biasp;
  const int col = lane & 15, rgrp = lane >> 4;
#pragma unroll
  for (int m = 0; m < 2; ++m) {
    int r0 = m0 + wr * 32 + m * 16 + rgrp * 4;
#pragma unroll
    for (int n = 0; n < 4; ++n) {
      int c = n0 + wc * 64 + n * 16 + col;
#pragma unroll
      for (int i = 0; i < 4; ++i)
        O[(size_t)(r0 + i) * Ss + c] = acc[m][n][i] + bias;
    }
  }
}

extern "C" void kernel_launch(void* const* d_in, const int* in_sizes, int n_in,
                              void* d_out, int out_size, void* d_ws,
                              size_t ws_size, hipStream_t stream) {
  const float* batch = (const float*)d_in[0];  // [32][512][1024]
  const float* projL = (const float*)d_in[1];  // [1024][256]
  const float* projR = (const float*)d_in[2];  // [256][1024]
  const float* bias = (const float*)d_in[3];   // [1]
  float* out = (float*)d_out;                  // [32][512][512]

  char* ws = (char*)d_ws;
  __bf16* left = (__bf16*)(ws);                 // 8,388,608 B [16384][256]
  __bf16* right = (__bf16*)(ws + 8388608);      // 8,388,608 B [16384][256]
  __bf16* Btc = (__bf16*)(ws + 16777216);       // 1,048,576 B [512][1024]

  prep_kernel<<<dim3(2048), dim3(256), 0, stream>>>(projL, projR, Btc);
  proj_gemm<<<dim3(512), dim3(256), 0, stream>>>(batch, Btc, left, right);
  score_gemm<<<dim3(4, 8, 32), dim3(256), 0, stream>>>(left, right, bias, out);
}

// Round 15
// 54.178 us; speedup vs baseline: 1.6808x; 1.6808x over previous
//
#include <hip/hip_runtime.h>
#include <hip/hip_bf16.h>
#include <stdint.h>

typedef __attribute__((ext_vector_type(8))) __bf16 bf16x8;
typedef __attribute__((ext_vector_type(4))) float f32x4;

static constexpr int Bb = 32, Ss = 512, Dd = 1024, Rr = 256;

__device__ __forceinline__ void gload_lds16(const void* g, void* l) {
  __builtin_amdgcn_global_load_lds(
      (const __attribute__((address_space(1))) void*)g,
      (__attribute__((address_space(3))) void*)l, 16, 0, 0);
}

// ---- prep: Bt[512][1024] bf16. rows 0-255 = L^T, rows 256-511 = R ----------
__global__ __launch_bounds__(256) void prep_kernel(
    const float* __restrict__ L, const float* __restrict__ R,
    __bf16* __restrict__ Bt) {
  int i = blockIdx.x * 256 + threadIdx.x;  // 0 .. 512*1024-1 exactly
  int n = i >> 10;
  int d = i & (Dd - 1);
  float v = (n < Rr) ? L[d * Rr + n] : R[(size_t)(n - Rr) * Dd + d];
  Bt[i] = (__bf16)v;
}

// ---- stage 1: C[16384,512] = batch_f32[16384,1024] x Bt[512,1024]^T --------
// 2-deep never-drain pipeline, FIXED (R14 bug: single areg stage clobbered
// by issueA(t+2) before writeA(t+1) consumed it). Now TWO named A-reg stages
// (aE/aO, parity = tile parity, compile-time selected via 2x-unrolled body).
// Iter t: {stageB(t+2) DMA + issueA(t+2)->stage(t%2)} -> writeA(t+1) from the
// OTHER stage (compiler-counted vmcnt(6) retires through issueA(t+1), which
// transitively retires B(t)'s DMAs) -> lgkmcnt(0) -> barrier -> compute(t).
// Quad-buffered LDS: write(t+2)/ds_write(t+1) vs slowest compute(t): buffer
// distances 2,3 mod 4 != 0. One full drain only at the tail.
// BM=64 BN=256 BK=32, 4 waves (32x128), 512 blocks = 2/CU, LDS 80KB.
__global__ __launch_bounds__(256, 2) void proj_gemm(
    const float* __restrict__ batch,
    const __bf16* __restrict__ Bt,   // [512][1024]
    __bf16* __restrict__ outL,       // [16384][256]
    __bf16* __restrict__ outR) {     // [16384][256]
  const int s = ((blockIdx.x & 7) << 6) + (blockIdx.x >> 3);
  const int mt = s >> 1;   // 0..255
  const int ntb = s & 1;   // 0..1
  const int m0 = mt * 64, n0 = ntb * 256;

  __shared__ __align__(16) char smem[81920];
  // buf q at q*20480: A bf16 [64][32] (4KB) then B bf16 [256][32] (16KB)

  const int t = threadIdx.x;
  const int lane = t & 63;
  const int wave = t >> 6;
  const int wr = wave >> 1, wc = wave & 1;  // 2x2 waves, 32x128 each

  f32x4 acc[2][8] = {};

  const int arow = t >> 2, ag = t & 3;
  const int ags = ag ^ ((arow >> 1) & 3);
  f32x4 aE0, aE1, aO0, aO1;  // two named stages (even/odd tiles)

  const float* abase = batch + (size_t)(m0 + arow) * Dd + ag * 8;

  auto issueAE = [&](int k0) {
    aE0 = *(const f32x4*)(abase + k0);
    aE1 = *(const f32x4*)(abase + k0 + 4);
  };
  auto issueAO = [&](int k0) {
    aO0 = *(const f32x4*)(abase + k0);
    aO1 = *(const f32x4*)(abase + k0 + 4);
  };
  auto writeAE = [&](int buf) {
    bf16x8 v;
    v[0] = (__bf16)aE0[0]; v[1] = (__bf16)aE0[1];
    v[2] = (__bf16)aE0[2]; v[3] = (__bf16)aE0[3];
    v[4] = (__bf16)aE1[0]; v[5] = (__bf16)aE1[1];
    v[6] = (__bf16)aE1[2]; v[7] = (__bf16)aE1[3];
    *(bf16x8*)(smem + buf * 20480 + (arow * 4 + ags) * 16) = v;
  };
  auto writeAO = [&](int buf) {
    bf16x8 v;
    v[0] = (__bf16)aO0[0]; v[1] = (__bf16)aO0[1];
    v[2] = (__bf16)aO0[2]; v[3] = (__bf16)aO0[3];
    v[4] = (__bf16)aO1[0]; v[5] = (__bf16)aO1[1];
    v[6] = (__bf16)aO1[2]; v[7] = (__bf16)aO1[3];
    *(bf16x8*)(smem + buf * 20480 + (arow * 4 + ags) * 16) = v;
  };
  auto stageB = [&](int buf, int k0) {
    char* Bbuf = smem + buf * 20480 + 4096;
#pragma unroll
    for (int p = 0; p < 4; ++p) {
      int e = p * 256 + t;
      int row = e >> 2, g = e & 3;
      int gs = g ^ ((row >> 1) & 3);
      gload_lds16(Bt + (size_t)(n0 + row) * Dd + k0 + gs * 8, Bbuf + e * 16);
    }
  };
  auto compute = [&](int buf) {
    const char* Ab = smem + buf * 20480;
    const char* Bbuf = smem + buf * 20480 + 4096;
    const int g = lane >> 4;
    bf16x8 a[2], b[8];
#pragma unroll
    for (int m = 0; m < 2; ++m) {
      int row = wr * 32 + m * 16 + (lane & 15);
      a[m] = *(const bf16x8*)(Ab + (row * 4 + (g ^ ((row >> 1) & 3))) * 16);
    }
#pragma unroll
    for (int n = 0; n < 8; ++n) {
      int row = wc * 128 + n * 16 + (lane & 15);
      b[n] = *(const bf16x8*)(Bbuf + (row * 4 + (g ^ ((row >> 1) & 3))) * 16);
    }
#pragma unroll
    for (int m = 0; m < 2; ++m)
#pragma unroll
      for (int n = 0; n < 8; ++n)
        acc[m][n] = __builtin_amdgcn_mfma_f32_16x16x32_bf16(a[m], b[n],
                                                            acc[m][n], 0, 0, 0);
  };

  // prologue: tile0 (stage E) fully staged; tile1 (stage O) issued
  stageB(0, 0);
  issueAE(0);
  writeAE(0);  // compiler waits for aE -> drains tile0 (prologue-only drain)
  stageB(1, 32);
  issueAO(32);
  asm volatile("s_waitcnt lgkmcnt(0)" ::: "memory");
  __builtin_amdgcn_s_barrier();

#pragma unroll 1
  for (int tt = 0; tt < 32; tt += 2) {
    // ---- even body: tile tt ----
    if (tt + 2 < 32) {
      stageB((tt + 2) & 3, tt * 32 + 64);
      issueAE(tt * 32 + 64);           // tile tt+2 (even) -> stage E
    }
    if (tt + 1 < 32) writeAO((tt + 1) & 3);  // tile tt+1 (odd) <- stage O
    asm volatile("s_waitcnt lgkmcnt(0)" ::: "memory");
    if (tt + 1 >= 32) asm volatile("s_waitcnt vmcnt(0)" ::: "memory");
    __builtin_amdgcn_s_barrier();
    compute(tt & 3);

    // ---- odd body: tile tt+1 ----
    if (tt + 3 < 32) {
      stageB((tt + 3) & 3, tt * 32 + 96);
      issueAO(tt * 32 + 96);           // tile tt+3 (odd) -> stage O
    }
    if (tt + 2 < 32) writeAE((tt + 2) & 3);  // tile tt+2 (even) <- stage E
    asm volatile("s_waitcnt lgkmcnt(0)" ::: "memory");
    if (tt + 2 >= 32) asm volatile("s_waitcnt vmcnt(0)" ::: "memory");
    __builtin_amdgcn_s_barrier();
    compute((tt + 1) & 3);
  }

  // epilogue
  __bf16* out = ntb ? outR : outL;
  const int col = lane & 15, rgrp = lane >> 4;
#pragma unroll
  for (int m = 0; m < 2; ++m) {
    int r0 = m0 + wr * 32 + m * 16 + rgrp * 4;
#pragma unroll
    for (int n = 0; n < 8; ++n) {
      int c = wc * 128 + n * 16 + col;
#pragma unroll
      for (int i = 0; i < 4; ++i)
        out[(size_t)(r0 + i) * Rr + c] = (__bf16)acc[m][n][i];
    }
  }
}

// ---- stage 2: logits[b] = left[b] @ right[b]^T + bias ----------------------
// UNCHANGED control (~614 TF measured).
__global__ __launch_bounds__(256, 4) void score_gemm(
    const __bf16* __restrict__ left,
    const __bf16* __restrict__ right,
    const float* __restrict__ biasp,
    float* __restrict__ out) {
  const int nt = blockIdx.x;  // 0..3
  const int mt = blockIdx.y;  // 0..7
  const int bz = blockIdx.z;  // 0..31
  const __bf16* A = left + (size_t)bz * Ss * Rr;
  const __bf16* B = right + (size_t)bz * Ss * Rr;
  float* O = out + (size_t)bz * Ss * Ss;
  const int m0 = mt * 64, n0 = nt * 128;

  __shared__ __align__(16) char smem[24576];
  const int t = threadIdx.x;
  const int lane = t & 63;
  const int wave = t >> 6;
  const int wr = wave >> 1, wc = wave & 1;

  f32x4 acc[2][4] = {};

  for (int it = 0; it < 4; ++it) {
    const int k0 = it * 64;
    __syncthreads();
#pragma unroll
    for (int q = 0; q < 2; ++q) {
      int e = q * 256 + t;
      int row = e >> 3, g = e & 7;
      int gsrc = g ^ (row & 7);
      gload_lds16(A + (size_t)(m0 + row) * Rr + k0 + gsrc * 8, smem + e * 16);
    }
#pragma unroll
    for (int q = 0; q < 4; ++q) {
      int e = q * 256 + t;
      int row = e >> 3, g = e & 7;
      int gsrc = g ^ (row & 7);
      gload_lds16(B + (size_t)(n0 + row) * Rr + k0 + gsrc * 8,
                  smem + 8192 + e * 16);
    }
    __syncthreads();

#pragma unroll
    for (int kk = 0; kk < 2; ++kk) {
      bf16x8 a[2], b[4];
#pragma unroll
      for (int m = 0; m < 2; ++m) {
        int row = wr * 32 + m * 16 + (lane & 15);
        int g = kk * 4 + (lane >> 4);
        a[m] = *(const bf16x8*)(smem + (row * 8 + (g ^ (row & 7))) * 16);
      }
#pragma unroll
      for (int n = 0; n < 4; ++n) {
        int row = wc * 64 + n * 16 + (lane & 15);
        int g = kk * 4 + (lane >> 4);
        b[n] = *(const bf16x8*)(smem + 8192 +
                                (row * 8 + (g ^ (row & 7))) * 16);
      }
#pragma unroll
      for (int m = 0; m < 2; ++m)
#pragma unroll
        for (int n = 0; n < 4; ++n)
          acc[m][n] = __builtin_amdgcn_mfma_f32_16x16x32_bf16(a[m], b[n],
                                                              acc[m][n], 0, 0, 0);
    }
  }

  const float bias = *biasp;
  const int col = lane & 15, rgrp = lane >> 4;
#pragma unroll
  for (int m = 0; m < 2; ++m) {
    int r0 = m0 + wr * 32 + m * 16 + rgrp * 4;
#pragma unroll
    for (int n = 0; n < 4; ++n) {
      int c = n0 + wc * 64 + n * 16 + col;
#pragma unroll
      for (int i = 0; i < 4; ++i)
        O[(size_t)(r0 + i) * Ss + c] = acc[m][n][i] + bias;
    }
  }
}

extern "C" void kernel_launch(void* const* d_in, const int* in_sizes, int n_in,
                              void* d_out, int out_size, void* d_ws,
                              size_t ws_size, hipStream_t stream) {
  const float* batch = (const float*)d_in[0];  // [32][512][1024]
  const float* projL = (const float*)d_in[1];  // [1024][256]
  const float* projR = (const float*)d_in[2];  // [256][1024]
  const float* bias = (const float*)d_in[3];   // [1]
  float* out = (float*)d_out;                  // [32][512][512]

  char* ws = (char*)d_ws;
  __bf16* left = (__bf16*)(ws);                 // 8,388,608 B [16384][256]
  __bf16* right = (__bf16*)(ws + 8388608);      // 8,388,608 B [16384][256]
  __bf16* Btc = (__bf16*)(ws + 16777216);       // 1,048,576 B [512][1024]

  prep_kernel<<<dim3(2048), dim3(256), 0, stream>>>(projL, projR, Btc);
  proj_gemm<<<dim3(512), dim3(256), 0, stream>>>(batch, Btc, left, right);
  score_gemm<<<dim3(4, 8, 32), dim3(256), 0, stream>>>(left, right, bias, out);
}